// Round 10
// baseline (4399.204 us; speedup 1.0000x reference)
//
#include <hip/hip_runtime.h>

#define NBATCH 128
#define DMODEL 512
#define FDIM 64
#define KIN 1024
#define NOUT 2048

typedef __attribute__((ext_vector_type(8))) short bf16x8;
typedef __attribute__((ext_vector_type(4))) float f32x4;
typedef __attribute__((ext_vector_type(4))) unsigned int u32x4;
typedef __attribute__((ext_vector_type(2))) unsigned int u32x2;

struct Par {
  const float *input, *mask, *Wi, *bi, *gi, *bti;
  const float *Wd1, *bd1, *Wd2, *bd2;
  const float *Wc1, *bc1, *Wc2, *bc2, *gc, *btc;
  float *out;
  float *cs, *ct, *logits;
  unsigned short *xhi, *xlo, *hhi, *hlo, *w1f, *w2f;
  int *pos, *ksel;
  unsigned int *flags;
};

#define W1PLANE 2097152u   // 128*32*512 u16 per plane
#define W2PLANE 4194304u   // 128*64*512 u16 per plane

__device__ __forceinline__ float gelu_f(float v) {
  float u = 0.7978845608028654f * (v + 0.044715f * v * v * v);
  return 0.5f * v * (1.0f + tanhf(u));
}
__device__ __forceinline__ float sigm_f(float v) { return 1.0f / (1.0f + expf(-v)); }

__device__ __forceinline__ float wred_sum(float v) {
#pragma unroll
  for (int o = 32; o > 0; o >>= 1) v += __shfl_xor(v, o, 64);
  return v;
}

__device__ __forceinline__ unsigned short bf16rn(float v) {
  unsigned int u = __float_as_uint(v);
  return (unsigned short)((u + 0x7FFFu + ((u >> 16) & 1u)) >> 16);
}
__device__ __forceinline__ float bf16hi_f(unsigned short h) {
  return __uint_as_float(((unsigned int)h) << 16);
}

// ---- system-coherent + NON-TEMPORAL (no L1/L2 allocate) stream accessors.
// nt keeps streams out of L2 so each XCD's L2 holds only its weight slice.
__device__ __forceinline__ void ldx4_sys4(const void* p0, const void* p1,
                                          const void* p2, const void* p3,
                                          u32x4& a, u32x4& b, u32x4& c, u32x4& d) {
  asm volatile(
      "global_load_dwordx4 %0, %4, off sc0 sc1 nt\n\t"
      "global_load_dwordx4 %1, %5, off sc0 sc1 nt\n\t"
      "global_load_dwordx4 %2, %6, off sc0 sc1 nt\n\t"
      "global_load_dwordx4 %3, %7, off sc0 sc1 nt\n\t"
      "s_waitcnt vmcnt(0)"
      : "=&v"(a), "=&v"(b), "=&v"(c), "=&v"(d)
      : "v"(p0), "v"(p1), "v"(p2), "v"(p3)
      : "memory");
}
__device__ __forceinline__ void ld1_sys4(const void* p0, const void* p1,
                                         const void* p2, const void* p3,
                                         unsigned int& a, unsigned int& b,
                                         unsigned int& c, unsigned int& d) {
  asm volatile(
      "global_load_dword %0, %4, off sc0 sc1 nt\n\t"
      "global_load_dword %1, %5, off sc0 sc1 nt\n\t"
      "global_load_dword %2, %6, off sc0 sc1 nt\n\t"
      "global_load_dword %3, %7, off sc0 sc1 nt\n\t"
      "s_waitcnt vmcnt(0)"
      : "=&v"(a), "=&v"(b), "=&v"(c), "=&v"(d)
      : "v"(p0), "v"(p1), "v"(p2), "v"(p3)
      : "memory");
}
__device__ __forceinline__ unsigned int ld1_sys(const void* p) {
  unsigned int r;
  asm volatile("global_load_dword %0, %1, off sc0 sc1 nt\n\ts_waitcnt vmcnt(0)"
               : "=&v"(r) : "v"(p) : "memory");
  return r;
}
__device__ __forceinline__ void st1_sys(void* p, unsigned int v) {
  asm volatile("global_store_dword %0, %1, off sc0 sc1 nt" :: "v"(p), "v"(v) : "memory");
}
__device__ __forceinline__ void st2_sys(void* p, u32x2 v) {
  asm volatile("global_store_dwordx2 %0, %1, off sc0 sc1 nt" :: "v"(p), "v"(v) : "memory");
}
__device__ __forceinline__ void st4_sys(void* p, u32x4 v) {
  asm volatile("global_store_dwordx4 %0, %1, off sc0 sc1 nt" :: "v"(p), "v"(v) : "memory");
}
__device__ __forceinline__ void sth_sys(void* p, unsigned int v) {
  asm volatile("global_store_short %0, %1, off sc0 sc1 nt" :: "v"(p), "v"(v) : "memory");
}

// ---- flag-array grid barrier: monotonic counters, bypass+nt stores/loads,
// no atomics, no cache invalidation (weights stay in L2).
__device__ __forceinline__ void gsync(unsigned int* flags, unsigned int* tgt) {
  unsigned int target = ++(*tgt);
  asm volatile("s_waitcnt vmcnt(0) lgkmcnt(0)" ::: "memory");
  __syncthreads();  // all threads' bypass stores drained
  int t = threadIdx.x;
  if (t == 0) st1_sys(&flags[blockIdx.x], target);
  if (t < 256) {
    while (ld1_sys(&flags[t]) < target) __builtin_amdgcn_s_sleep(2);
  }
  __syncthreads();
}

// ---- SEL: argmax + pos/logit shift; emit x = [l,r] as bf16 hi/lo planes + LDS fp32 stash
__device__ void sel_phase(const Par& p, int i, int* sI, float* smem) {
  int n = blockIdx.x;
  int t = threadIdx.x, wave = t >> 6, lane = t & 63;
  int P = 63 - i;
  if (wave == 0) {
    float v = -3.0e38f;
    int idx = 1 << 20;
    if (lane < P) {
      v = p.logits[n * 64 + lane];
      float mk = p.mask[n * 64 + i + 1 + lane];
      if (!(mk > 0.0f)) v = -1.0e9f;
      idx = lane;
    }
#pragma unroll
    for (int o = 32; o > 0; o >>= 1) {
      float v2 = __shfl_xor(v, o, 64);
      int i2 = __shfl_xor(idx, o, 64);
      if (v2 > v || (v2 == v && i2 < idx)) { v = v2; idx = i2; }
    }
    if (lane == 0) {
      p.ksel[n] = idx;
      sI[0] = idx;
      sI[1] = p.pos[n * 64 + idx];
      sI[2] = p.pos[n * 64 + idx + 1];
    }
  }
  __syncthreads();
  int k = sI[0], slot_l = sI[1], slot_r = sI[2];
  if (wave == 1) {  // shift pos (wave-lockstep load-before-store)
    int j = lane;
    if (j >= k + 1 && j <= 62 - i) {
      int tmp = p.pos[n * 64 + j + 1];
      p.pos[n * 64 + j] = tmp;
    }
  } else if (wave == 2) {  // shift logits
    int j = lane;
    if (j >= k && j <= 61 - i) {
      float tmp = p.logits[n * 64 + j + 1];
      p.logits[n * 64 + j] = tmp;
    }
  }
  float* sx = smem + 12544;  // survives g1/g2 (they use floats [0,12544))
  if (t < 256) {
    const float* srcp = (t < 128) ? &p.cs[(size_t)(n * 64 + slot_l) * DMODEL]
                                  : &p.cs[(size_t)(n * 64 + slot_r) * DMODEL];
    int so = (t & 127) * 4;
    int o = (t < 128) ? so : (512 + so);
    float4 v = *(const float4*)&srcp[so];
    *(float4*)&sx[o] = v;
    ushort4 hi, lo;
    hi.x = bf16rn(v.x); lo.x = bf16rn(v.x - bf16hi_f(hi.x));
    hi.y = bf16rn(v.y); lo.y = bf16rn(v.y - bf16hi_f(hi.y));
    hi.z = bf16rn(v.z); lo.z = bf16rn(v.z - bf16hi_f(hi.z));
    hi.w = bf16rn(v.w); lo.w = bf16rn(v.w - bf16hi_f(hi.w));
    u32x2 uh, ul;
    uh.x = (unsigned)hi.x | ((unsigned)hi.y << 16);
    uh.y = (unsigned)hi.z | ((unsigned)hi.w << 16);
    ul.x = (unsigned)lo.x | ((unsigned)lo.y << 16);
    ul.y = (unsigned)lo.z | ((unsigned)lo.w << 16);
    st2_sys(&p.xhi[(size_t)n * KIN + o], uh);
    st2_sys(&p.xlo[(size_t)n * KIN + o], ul);
  }
}

// ---- split-bf16 MFMA GEMM (A via nt bypass loads; B-frags via plain cached
// loads -> resident in XCD-pinned L2, now unpolluted by streams)
__device__ void gemm_mfma(const unsigned short* Ahi, const unsigned short* Alo,
                          const unsigned short* Bf, unsigned int bplane,
                          const float* bias, int K, int KS, int NCH, bool do_gelu,
                          unsigned short* Yhi, unsigned short* Ylo, float* Yf32,
                          float* smem) {
  int b = blockIdx.x, t = threadIdx.x;
  int m = (b >> 3) & 7;
  int ng = ((b >> 6) << 3) | (b & 7);
  int rbase = m * 16;
  int w = t >> 6, lane = t & 63;
  int tile = w & 3, hv = w >> 2;
  int quad = lane >> 4, mr = lane & 15;
  int nt = ng * 4 + tile;
  int cbase = nt * 16;
  unsigned short* As = (unsigned short*)smem;  // [pl][hv][16][264] u16
  float* red = smem + 8448;                    // 4096 floats
  int KH = K >> 1;
  f32x4 acc = {0.f, 0.f, 0.f, 0.f};
  const unsigned short* bp0 = Bf + (size_t)nt * KS * 512 + lane * 8;
  const unsigned short* bp1 = bp0 + bplane;
  for (int ch = 0; ch < NCH; ++ch) {
    __syncthreads();
    const void* ap[4];
    int lo_[4];
#pragma unroll
    for (int q = 0; q < 4; ++q) {  // stage A: 2 planes x 2 k-halves x 16 rows x 256
      int g = q * 512 + t;
      int pl = g >> 10, hh = (g >> 9) & 1, r = (g >> 5) & 15, kg = g & 31;
      ap[q] = (pl ? Alo : Ahi) + (size_t)(rbase + r) * K + hh * KH + ch * 256 + kg * 8;
      lo_[q] = ((pl * 2 + hh) * 16 + r) * 264 + kg * 8;
    }
    u32x4 v0, v1, v2, v3;
    ldx4_sys4(ap[0], ap[1], ap[2], ap[3], v0, v1, v2, v3);
    *(u32x4*)&As[lo_[0]] = v0;
    *(u32x4*)&As[lo_[1]] = v1;
    *(u32x4*)&As[lo_[2]] = v2;
    *(u32x4*)&As[lo_[3]] = v3;
    __syncthreads();
    int ks0 = hv * (KS >> 1) + ch * 8;
    const unsigned short* a0 = &As[(hv * 16 + mr) * 264 + quad * 8];
    const unsigned short* a1 = &As[((2 + hv) * 16 + mr) * 264 + quad * 8];
#pragma unroll
    for (int s = 0; s < 8; ++s) {
      bf16x8 ah = *(const bf16x8*)(a0 + s * 32);
      bf16x8 al = *(const bf16x8*)(a1 + s * 32);
      bf16x8 bh = *(const bf16x8*)(bp0 + (size_t)(ks0 + s) * 512);
      bf16x8 bl = *(const bf16x8*)(bp1 + (size_t)(ks0 + s) * 512);
      acc = __builtin_amdgcn_mfma_f32_16x16x32_bf16(ah, bh, acc, 0, 0, 0);
      acc = __builtin_amdgcn_mfma_f32_16x16x32_bf16(ah, bl, acc, 0, 0, 0);
      acc = __builtin_amdgcn_mfma_f32_16x16x32_bf16(al, bh, acc, 0, 0, 0);
    }
  }
  if (hv == 1) *(f32x4*)&red[(tile * 64 + lane) * 4] = acc;
  __syncthreads();
  if (hv == 0) {
    f32x4 o4 = *(const f32x4*)&red[(tile * 64 + lane) * 4];
    float bb = bias[cbase + mr];
#pragma unroll
    for (int r = 0; r < 4; ++r) {
      float o = acc[r] + o4[r] + bb;
      int row = rbase + quad * 4 + r;  // C/D: col=lane&15, row=quad*4+reg
      if (do_gelu) {
        o = gelu_f(o);
        unsigned short h = bf16rn(o);
        unsigned short l = bf16rn(o - bf16hi_f(h));
        sth_sys(&Yhi[(size_t)row * NOUT + cbase + mr], (unsigned int)h);
        sth_sys(&Ylo[(size_t)row * NOUT + cbase + mr], (unsigned int)l);
      } else {
        st1_sys(&Yf32[(size_t)row * NOUT + cbase + mr], __float_as_uint(o));
      }
    }
  }
}

// ---- EPI: gates/blend/LN -> cs[slot_new]; recompute logits for pairs k-1, k
__device__ void epi_phase(const Par& p, int i, float* smem, float* sred) {
  int n = blockIdx.x;
  int t = threadIdx.x, wave = t >> 6, lane = t & 63;
  int Pn = 62 - i;
  int k = p.ksel[n];
  int slot_new = p.pos[n * 64 + k];
  float* s_wd1 = smem;          // [0, 8192)
  float* s_wd2 = smem + 8192;   // 64
  float* s_bd1 = smem + 8256;   // 64
  float* s_fnew = smem + 8320;  // 64
  float* sx = smem + 12544;     // x-row stash from sel
  if (i < 62) {
#pragma unroll
    for (int q = 0; q < 4; ++q)
      ((float4*)s_wd1)[q * 512 + t] = ((const float4*)p.Wd1)[q * 512 + t];
    if (t < 64) { s_wd2[t] = p.Wd2[t]; s_bd1[t] = p.bd1[t]; }
  }
  const float* ct = p.ct + (size_t)n * NOUT;
  int d = t;
  float lv = sx[d];
  float rv = sx[512 + d];
  unsigned int u0, u1, u2, u3;
  ld1_sys4(&ct[d], &ct[DMODEL + d], &ct[2 * DMODEL + d], &ct[3 * DMODEL + d],
           u0, u1, u2, u3);
  float c0 = __uint_as_float(u0), c1 = __uint_as_float(u1);
  float c2 = __uint_as_float(u2), c3 = __uint_as_float(u3);
  float s = sigm_f(c0) * lv + sigm_f(c1) * rv + sigm_f(c2) * c3;
  float part = wred_sum(s);
  if (lane == 0) sred[wave] = part;
  __syncthreads();
  float mm = 0.f;
#pragma unroll
  for (int ww = 0; ww < 8; ++ww) mm += sred[ww];
  mm *= (1.0f / 512.0f);
  float e = s - mm;
  float pq = wred_sum(e * e);
  if (lane == 0) sred[8 + wave] = pq;
  __syncthreads();
  float var = 0.f;
#pragma unroll
  for (int ww = 0; ww < 8; ++ww) var += sred[8 + ww];
  var *= (1.0f / 512.0f);
  float inv = 1.0f / sqrtf(var + 1e-5f);
  float nv = e * inv * p.gc[d] + p.btc[d];
  p.cs[(size_t)(n * 64 + slot_new) * DMODEL + d] = nv;  // block-local, cached
  if (i == 62) p.out[(size_t)n * DMODEL + d] = nv;
  if (d < FDIM) s_fnew[d] = nv;
  __syncthreads();
  if (i < 62) {
    if (wave == 0 && k >= 1) {
      const float* A = &p.cs[(size_t)(n * 64 + p.pos[n * 64 + (k - 1)]) * DMODEL];
      float hs = s_bd1[lane];
#pragma unroll 8
      for (int kk = 0; kk < 64; ++kk) hs += A[kk] * s_wd1[kk * 64 + lane];
#pragma unroll 8
      for (int kk = 0; kk < 64; ++kk) hs += s_fnew[kk] * s_wd1[(64 + kk) * 64 + lane];
      float g = wred_sum(gelu_f(hs) * s_wd2[lane]);
      if (lane == 0) p.logits[n * 64 + (k - 1)] = g + p.bd2[0];
    } else if (wave == 1 && k < Pn) {
      const float* Bv = &p.cs[(size_t)(n * 64 + p.pos[n * 64 + (k + 1)]) * DMODEL];
      float hs = s_bd1[lane];
#pragma unroll 8
      for (int kk = 0; kk < 64; ++kk) hs += s_fnew[kk] * s_wd1[kk * 64 + lane];
#pragma unroll 8
      for (int kk = 0; kk < 64; ++kk) hs += Bv[kk] * s_wd1[(64 + kk) * 64 + lane];
      float g = wred_sum(gelu_f(hs) * s_wd2[lane]);
      if (lane == 0) p.logits[n * 64 + k] = g + p.bd2[0];
    }
  }
}

__global__ void egt_zero(unsigned int* flags) { flags[threadIdx.x] = 0u; }

__global__ void __launch_bounds__(512, 2) egt_main(Par p) {
  __shared__ __align__(16) float smem[15872];  // 62 KB
  __shared__ float sred[16];
  __shared__ int sI[8];
  unsigned int nsync = 0;
  int b = blockIdx.x, t = threadIdx.x;
  int wave = t >> 6, lane = t & 63;

  // ---------- INIT-WTRANSFORM: Wc1/Wc2 fp32 -> B-frag-major bf16 hi/lo planes
  // (nt bypass stores -> LLC; loop's plain B loads re-allocate them into L2)
  {
    int tid = b * 512 + t;
    for (int it = tid; it < 786432; it += 131072) {
      const float* W;
      unsigned short *dh, *dl;
      int nt, ks, l, KS2;
      if (it < 262144) {
        W = p.Wc1; dh = p.w1f; dl = p.w1f + W1PLANE;
        nt = it >> 11; int r2 = it & 2047; ks = r2 >> 6; l = r2 & 63; KS2 = 32;
      } else {
        int rem = it - 262144;
        W = p.Wc2; dh = p.w2f; dl = p.w2f + W2PLANE;
        nt = rem >> 12; int r2 = rem & 4095; ks = r2 >> 6; l = r2 & 63; KS2 = 64;
      }
      int k0 = ks * 32 + (l >> 4) * 8;
      int n = nt * 16 + (l & 15);
      unsigned int hw[4], lw[4];
#pragma unroll
      for (int jj = 0; jj < 4; ++jj) {
        float v0 = W[(size_t)(k0 + 2 * jj) * NOUT + n];
        float v1 = W[(size_t)(k0 + 2 * jj + 1) * NOUT + n];
        unsigned short h0 = bf16rn(v0), h1 = bf16rn(v1);
        unsigned short l0 = bf16rn(v0 - bf16hi_f(h0));
        unsigned short l1 = bf16rn(v1 - bf16hi_f(h1));
        hw[jj] = (unsigned int)h0 | ((unsigned int)h1 << 16);
        lw[jj] = (unsigned int)l0 | ((unsigned int)l1 << 16);
      }
      size_t o = ((size_t)nt * KS2 + ks) * 512 + l * 8;
      u32x4 H; H.x = hw[0]; H.y = hw[1]; H.z = hw[2]; H.w = hw[3];
      u32x4 L; L.x = lw[0]; L.y = lw[1]; L.z = lw[2]; L.w = lw[3];
      st4_sys(&dh[o], H);
      st4_sys(&dl[o], L);
    }
  }

  // ---------- INIT-PROJ: cs0 = LN(input @ Wi + bi); 32 (n,s)-rows per block
  // (cs written via nt bypass stores; read later by a different block)
  {
    int rbase = b * 32;
    int n_ = b >> 1;
    float acc[32];
#pragma unroll
    for (int r = 0; r < 32; ++r) acc[r] = 0.f;
    float* xs = smem;  // [32][64]
    const float* Wi = p.Wi;
    for (int kc = 0; kc < 512; kc += 64) {
      __syncthreads();
      {
        int flat = t * 4;
        int r = flat >> 6, c = flat & 63;
        *(float4*)&xs[flat] =
            *(const float4*)&p.input[(size_t)(rbase + r) * 512 + kc + c];
      }
      __syncthreads();
      for (int k = 0; k < 64; k += 4) {
        float w0 = Wi[(size_t)(kc + k + 0) * 512 + t];
        float w1 = Wi[(size_t)(kc + k + 1) * 512 + t];
        float w2 = Wi[(size_t)(kc + k + 2) * 512 + t];
        float w3 = Wi[(size_t)(kc + k + 3) * 512 + t];
#pragma unroll
        for (int r = 0; r < 32; ++r) {
          float4 xv = *(const float4*)&xs[r * 64 + k];
          acc[r] += xv.x * w0 + xv.y * w1 + xv.z * w2 + xv.w * w3;
        }
      }
    }
    float* row8 = smem;  // [8][512]
#pragma unroll
    for (int chunk = 0; chunk < 4; ++chunk) {
      __syncthreads();
#pragma unroll
      for (int rr = 0; rr < 8; ++rr)
        row8[rr * 512 + t] = acc[chunk * 8 + rr] + p.bi[t];
      __syncthreads();
      int rr = wave;
      float vals[8];
      float sum = 0.f;
#pragma unroll
      for (int jj = 0; jj < 8; ++jj) {
        float v = row8[rr * 512 + jj * 64 + lane];
        vals[jj] = v;
        sum += v;
      }
      sum = wred_sum(sum);
      float mm = sum * (1.0f / 512.0f);
      float sq = 0.f;
#pragma unroll
      for (int jj = 0; jj < 8; ++jj) { float dd = vals[jj] - mm; sq += dd * dd; }
      sq = wred_sum(sq);
      float inv = 1.0f / sqrtf(sq * (1.0f / 512.0f) + 1e-5f);
      int r = chunk * 8 + rr;
      int ss = (b & 1) * 32 + r;
      float* dst = &p.cs[(size_t)(n_ * 64 + ss) * DMODEL];
#pragma unroll
      for (int jj = 0; jj < 8; ++jj) {
        int c = jj * 64 + lane;
        st1_sys(&dst[c], __float_as_uint((vals[jj] - mm) * inv * p.gi[c] + p.bti[c]));
      }
    }
  }
  gsync(p.flags, &nsync);

  // ---------- INIT-SCORE: 63 pair logits per row; init pos; SEL(0)
  if (b < NBATCH) {
    int n = b;
    float* s_wd1 = smem;          // 8192 floats
    float* s_f = smem + 8192;     // 4096 floats
    float* s_wd2 = smem + 12288;  // 64
    float* s_bd1 = smem + 12352;  // 64
#pragma unroll
    for (int q = 0; q < 4; ++q)
      ((float4*)s_wd1)[q * 512 + t] = ((const float4*)p.Wd1)[q * 512 + t];
#pragma unroll
    for (int q = 0; q < 2; ++q) {
      int i4 = q * 512 + t;
      int s = i4 >> 4, c = (i4 & 15) * 4;
      *(float4*)&s_f[s * 64 + c] =
          *(const float4*)&p.cs[(size_t)(n * 64 + s) * DMODEL + c];
    }
    if (t < 64) {
      s_wd2[t] = p.Wd2[t];
      s_bd1[t] = p.bd1[t];
      p.pos[n * 64 + t] = t;
    }
    __syncthreads();
    for (int pr = wave; pr < 63; pr += 8) {
      float hs = s_bd1[lane];
#pragma unroll 8
      for (int kk = 0; kk < 64; ++kk) hs += s_f[pr * 64 + kk] * s_wd1[kk * 64 + lane];
#pragma unroll 8
      for (int kk = 0; kk < 64; ++kk) hs += s_f[(pr + 1) * 64 + kk] * s_wd1[(64 + kk) * 64 + lane];
      float g = wred_sum(gelu_f(hs) * s_wd2[lane]);
      if (lane == 0) p.logits[n * 64 + pr] = g + p.bd2[0];
    }
    __syncthreads();
    sel_phase(p, 0, sI, smem);
  }
  gsync(p.flags, &nsync);

  // ---------- main serial loop
  for (int i = 0; i < 63; ++i) {
    gemm_mfma(p.xhi, p.xlo, p.w1f, W1PLANE, p.bc1, KIN, 32, 2, true,
              p.hhi, p.hlo, nullptr, smem);
    gsync(p.flags, &nsync);
    gemm_mfma(p.hhi, p.hlo, p.w2f, W2PLANE, p.bc2, NOUT, 64, 4, false,
              nullptr, nullptr, p.ct, smem);
    gsync(p.flags, &nsync);
    if (b < NBATCH) {
      epi_phase(p, i, smem, sred);
      if (i < 62) {
        __syncthreads();
        sel_phase(p, i + 1, sI, smem);
      }
    }
    gsync(p.flags, &nsync);
  }
}

extern "C" void kernel_launch(void* const* d_in, const int* in_sizes, int n_in,
                              void* d_out, int out_size, void* d_ws, size_t ws_size,
                              hipStream_t stream) {
  Par p;
  p.input = (const float*)d_in[0];
  p.mask = (const float*)d_in[1];
  p.Wi = (const float*)d_in[2];
  p.bi = (const float*)d_in[3];
  p.gi = (const float*)d_in[4];
  p.bti = (const float*)d_in[5];
  p.Wd1 = (const float*)d_in[6];
  p.bd1 = (const float*)d_in[7];
  p.Wd2 = (const float*)d_in[8];
  p.bd2 = (const float*)d_in[9];
  p.Wc1 = (const float*)d_in[10];
  p.bc1 = (const float*)d_in[11];
  p.Wc2 = (const float*)d_in[12];
  p.bc2 = (const float*)d_in[13];
  p.gc = (const float*)d_in[14];
  p.btc = (const float*)d_in[15];
  p.out = (float*)d_out;

  char* ws = (char*)d_ws;
  size_t off = 0;
  auto take = [&](size_t bytes) -> char* {
    char* r = ws + off;
    off += (bytes + 255) & ~(size_t)255;
    return r;
  };
  p.flags = (unsigned int*)take(1024);
  p.pos = (int*)take(128 * 64 * 4);
  p.ksel = (int*)take(128 * 4);
  p.logits = (float*)take(128 * 64 * 4);
  p.ct = (float*)take((size_t)128 * 2048 * 4);
  p.cs = (float*)take((size_t)128 * 64 * 512 * 4);
  p.xhi = (unsigned short*)take((size_t)128 * 1024 * 2);
  p.xlo = (unsigned short*)take((size_t)128 * 1024 * 2);
  p.hhi = (unsigned short*)take((size_t)128 * 2048 * 2);
  p.hlo = (unsigned short*)take((size_t)128 * 2048 * 2);
  p.w1f = (unsigned short*)take((size_t)2 * W1PLANE * 2);
  p.w2f = (unsigned short*)take((size_t)2 * W2PLANE * 2);
  // total ~43.5 MB of d_ws

  hipLaunchKernelGGL(egt_zero, dim3(1), dim3(256), 0, stream, p.flags);
  void* args[] = {&p};
  hipError_t err = hipLaunchCooperativeKernel(egt_main, dim3(256), dim3(512), args, 0, stream);
  if (err != hipSuccess) {
    (void)hipGetLastError();  // manual barrier works under plain launch too
    hipLaunchKernelGGL(egt_main, dim3(256), dim3(512), 0, stream, p);
  }
}

// Round 11
// 2688.918 us; speedup vs baseline: 1.6360x; 1.6360x over previous
//
#include <hip/hip_runtime.h>

#define NBATCH 128
#define DMODEL 512
#define FDIM 64
#define KIN 1024
#define NOUT 2048

typedef __attribute__((ext_vector_type(8))) short bf16x8;
typedef __attribute__((ext_vector_type(4))) float f32x4;
typedef __attribute__((ext_vector_type(4))) unsigned int u32x4;
typedef __attribute__((ext_vector_type(2))) unsigned int u32x2;

struct Par {
  const float *input, *mask, *Wi, *bi, *gi, *bti;
  const float *Wd1, *bd1, *Wd2, *bd2;
  const float *Wc1, *bc1, *Wc2, *bc2, *gc, *btc;
  float *out;
  float *cs, *ct, *logits;
  unsigned short *xhi, *xlo, *hhi, *hlo, *w1f, *w2f;
  int *pos, *ksel;
  unsigned int *flags;
};

#define W1PLANE 2097152u   // 128*32*512 u16 per plane
#define W2PLANE 4194304u   // 128*64*512 u16 per plane

__device__ __forceinline__ float gelu_f(float v) {
  float u = 0.7978845608028654f * (v + 0.044715f * v * v * v);
  return 0.5f * v * (1.0f + tanhf(u));
}
__device__ __forceinline__ float sigm_f(float v) { return 1.0f / (1.0f + expf(-v)); }

__device__ __forceinline__ float wred_sum(float v) {
#pragma unroll
  for (int o = 32; o > 0; o >>= 1) v += __shfl_xor(v, o, 64);
  return v;
}

__device__ __forceinline__ unsigned short bf16rn(float v) {
  unsigned int u = __float_as_uint(v);
  return (unsigned short)((u + 0x7FFFu + ((u >> 16) & 1u)) >> 16);
}
__device__ __forceinline__ float bf16hi_f(unsigned short h) {
  return __uint_as_float(((unsigned int)h) << 16);
}

// ---- system-coherent (L1/L2-bypass, LLC-allocating) stream accessors (r9 semantics).
__device__ __forceinline__ void ldx4_issue(const void* p0, const void* p1,
                                           const void* p2, const void* p3,
                                           u32x4& a, u32x4& b, u32x4& c, u32x4& d) {
  asm volatile(
      "global_load_dwordx4 %0, %4, off sc0 sc1\n\t"
      "global_load_dwordx4 %1, %5, off sc0 sc1\n\t"
      "global_load_dwordx4 %2, %6, off sc0 sc1\n\t"
      "global_load_dwordx4 %3, %7, off sc0 sc1"
      : "=&v"(a), "=&v"(b), "=&v"(c), "=&v"(d)
      : "v"(p0), "v"(p1), "v"(p2), "v"(p3)
      : "memory");
}
__device__ __forceinline__ void vm_wait0() {
  asm volatile("s_waitcnt vmcnt(0)" ::: "memory");
}
__device__ __forceinline__ void ld1_sys4(const void* p0, const void* p1,
                                         const void* p2, const void* p3,
                                         unsigned int& a, unsigned int& b,
                                         unsigned int& c, unsigned int& d) {
  asm volatile(
      "global_load_dword %0, %4, off sc0 sc1\n\t"
      "global_load_dword %1, %5, off sc0 sc1\n\t"
      "global_load_dword %2, %6, off sc0 sc1\n\t"
      "global_load_dword %3, %7, off sc0 sc1\n\t"
      "s_waitcnt vmcnt(0)"
      : "=&v"(a), "=&v"(b), "=&v"(c), "=&v"(d)
      : "v"(p0), "v"(p1), "v"(p2), "v"(p3)
      : "memory");
}
__device__ __forceinline__ unsigned int ld1_sys(const void* p) {
  unsigned int r;
  asm volatile("global_load_dword %0, %1, off sc0 sc1\n\ts_waitcnt vmcnt(0)"
               : "=&v"(r) : "v"(p) : "memory");
  return r;
}
__device__ __forceinline__ void st1_sys(void* p, unsigned int v) {
  asm volatile("global_store_dword %0, %1, off sc0 sc1" :: "v"(p), "v"(v) : "memory");
}
__device__ __forceinline__ void st2_sys(void* p, u32x2 v) {
  asm volatile("global_store_dwordx2 %0, %1, off sc0 sc1" :: "v"(p), "v"(v) : "memory");
}
__device__ __forceinline__ void st4_sys(void* p, u32x4 v) {
  asm volatile("global_store_dwordx4 %0, %1, off sc0 sc1" :: "v"(p), "v"(v) : "memory");
}
__device__ __forceinline__ void sth_sys(void* p, unsigned int v) {
  asm volatile("global_store_short %0, %1, off sc0 sc1" :: "v"(p), "v"(v) : "memory");
}

// ---- flag-array grid barrier: monotonic counters, bypass stores/loads,
// no atomics, no cache invalidation (weights stay in L2).
__device__ __forceinline__ void gsync(unsigned int* flags, unsigned int* tgt) {
  unsigned int target = ++(*tgt);
  asm volatile("s_waitcnt vmcnt(0) lgkmcnt(0)" ::: "memory");
  __syncthreads();  // all threads' bypass stores drained
  int t = threadIdx.x;
  if (t == 0) st1_sys(&flags[blockIdx.x], target);
  if (t < 256) {
    while (ld1_sys(&flags[t]) < target) __builtin_amdgcn_s_sleep(2);
  }
  __syncthreads();
}

// ---- SEL: argmax + pos/logit shift; emit x = [l,r] as bf16 hi/lo planes + LDS fp32 stash
__device__ void sel_phase(const Par& p, int i, int* sI, float* smem) {
  int n = blockIdx.x;
  int t = threadIdx.x, wave = t >> 6, lane = t & 63;
  int P = 63 - i;
  if (wave == 0) {
    float v = -3.0e38f;
    int idx = 1 << 20;
    if (lane < P) {
      v = p.logits[n * 64 + lane];
      float mk = p.mask[n * 64 + i + 1 + lane];
      if (!(mk > 0.0f)) v = -1.0e9f;
      idx = lane;
    }
#pragma unroll
    for (int o = 32; o > 0; o >>= 1) {
      float v2 = __shfl_xor(v, o, 64);
      int i2 = __shfl_xor(idx, o, 64);
      if (v2 > v || (v2 == v && i2 < idx)) { v = v2; idx = i2; }
    }
    if (lane == 0) {
      p.ksel[n] = idx;
      sI[0] = idx;
      sI[1] = p.pos[n * 64 + idx];
      sI[2] = p.pos[n * 64 + idx + 1];
    }
  }
  __syncthreads();
  int k = sI[0], slot_l = sI[1], slot_r = sI[2];
  if (wave == 1) {  // shift pos (wave-lockstep load-before-store)
    int j = lane;
    if (j >= k + 1 && j <= 62 - i) {
      int tmp = p.pos[n * 64 + j + 1];
      p.pos[n * 64 + j] = tmp;
    }
  } else if (wave == 2) {  // shift logits
    int j = lane;
    if (j >= k && j <= 61 - i) {
      float tmp = p.logits[n * 64 + j + 1];
      p.logits[n * 64 + j] = tmp;
    }
  }
  float* sx = smem + 12544;  // survives g1/g2 (they use floats [0,12544))
  if (t < 256) {
    const float* srcp = (t < 128) ? &p.cs[(size_t)(n * 64 + slot_l) * DMODEL]
                                  : &p.cs[(size_t)(n * 64 + slot_r) * DMODEL];
    int so = (t & 127) * 4;
    int o = (t < 128) ? so : (512 + so);
    float4 v = *(const float4*)&srcp[so];
    *(float4*)&sx[o] = v;
    ushort4 hi, lo;
    hi.x = bf16rn(v.x); lo.x = bf16rn(v.x - bf16hi_f(hi.x));
    hi.y = bf16rn(v.y); lo.y = bf16rn(v.y - bf16hi_f(hi.y));
    hi.z = bf16rn(v.z); lo.z = bf16rn(v.z - bf16hi_f(hi.z));
    hi.w = bf16rn(v.w); lo.w = bf16rn(v.w - bf16hi_f(hi.w));
    u32x2 uh, ul;
    uh.x = (unsigned)hi.x | ((unsigned)hi.y << 16);
    uh.y = (unsigned)hi.z | ((unsigned)hi.w << 16);
    ul.x = (unsigned)lo.x | ((unsigned)lo.y << 16);
    ul.y = (unsigned)lo.z | ((unsigned)lo.w << 16);
    st2_sys(&p.xhi[(size_t)n * KIN + o], uh);
    st2_sys(&p.xlo[(size_t)n * KIN + o], ul);
  }
}

// ---- split-bf16 MFMA GEMM with cross-chunk A-prefetch (issue during MFMA of
// previous chunk) and per-chunk B-preload into registers.
__device__ void gemm_mfma(const unsigned short* Ahi, const unsigned short* Alo,
                          const unsigned short* Bf, unsigned int bplane,
                          const float* bias, int K, int KS, int NCH, bool do_gelu,
                          unsigned short* Yhi, unsigned short* Ylo, float* Yf32,
                          float* smem) {
  int b = blockIdx.x, t = threadIdx.x;
  int m = (b >> 3) & 7;
  int ng = ((b >> 6) << 3) | (b & 7);
  int rbase = m * 16;
  int w = t >> 6, lane = t & 63;
  int tile = w & 3, hv = w >> 2;
  int quad = lane >> 4, mr = lane & 15;
  int nt = ng * 4 + tile;
  int cbase = nt * 16;
  unsigned short* As = (unsigned short*)smem;  // [pl][hv][16][264] u16
  float* red = smem + 8448;                    // 4096 floats
  int KH = K >> 1;
  f32x4 acc = {0.f, 0.f, 0.f, 0.f};
  const unsigned short* bp0 = Bf + (size_t)nt * KS * 512 + lane * 8;
  const unsigned short* bp1 = bp0 + bplane;
  // per-thread staging address components (chunk-invariant)
  const unsigned short* srcb[4];
  size_t aoff[4];
  int lo_[4];
#pragma unroll
  for (int q = 0; q < 4; ++q) {
    int g = q * 512 + t;
    int pl = g >> 10, hh = (g >> 9) & 1, r = (g >> 5) & 15, kg = g & 31;
    srcb[q] = pl ? Alo : Ahi;
    aoff[q] = (size_t)(rbase + r) * K + hh * KH + kg * 8;
    lo_[q] = ((pl * 2 + hh) * 16 + r) * 264 + kg * 8;
  }
  u32x4 c0, c1, c2, c3, n0, n1, n2, n3;
  ldx4_issue(srcb[0] + aoff[0], srcb[1] + aoff[1], srcb[2] + aoff[2],
             srcb[3] + aoff[3], c0, c1, c2, c3);
  vm_wait0();
  for (int ch = 0; ch < NCH; ++ch) {
    __syncthreads();  // previous chunk's readers done
    *(u32x4*)&As[lo_[0]] = c0;
    *(u32x4*)&As[lo_[1]] = c1;
    *(u32x4*)&As[lo_[2]] = c2;
    *(u32x4*)&As[lo_[3]] = c3;
    __syncthreads();  // tile visible
    if (ch + 1 < NCH) {  // prefetch next chunk's A (in flight during MFMA)
      size_t o = (size_t)(ch + 1) * 256;
      ldx4_issue(srcb[0] + aoff[0] + o, srcb[1] + aoff[1] + o,
                 srcb[2] + aoff[2] + o, srcb[3] + aoff[3] + o, n0, n1, n2, n3);
    }
    int ks0 = hv * (KS >> 1) + ch * 8;
    const unsigned short* a0 = &As[(hv * 16 + mr) * 264 + quad * 8];
    const unsigned short* a1 = &As[((2 + hv) * 16 + mr) * 264 + quad * 8];
    bf16x8 bhv[8], blv[8];
#pragma unroll
    for (int s = 0; s < 8; ++s) {  // batch B loads (L2 hits, latency batched)
      bhv[s] = *(const bf16x8*)(bp0 + (size_t)(ks0 + s) * 512);
      blv[s] = *(const bf16x8*)(bp1 + (size_t)(ks0 + s) * 512);
    }
#pragma unroll
    for (int s = 0; s < 8; ++s) {
      bf16x8 ah = *(const bf16x8*)(a0 + s * 32);
      bf16x8 al = *(const bf16x8*)(a1 + s * 32);
      acc = __builtin_amdgcn_mfma_f32_16x16x32_bf16(ah, bhv[s], acc, 0, 0, 0);
      acc = __builtin_amdgcn_mfma_f32_16x16x32_bf16(ah, blv[s], acc, 0, 0, 0);
      acc = __builtin_amdgcn_mfma_f32_16x16x32_bf16(al, bhv[s], acc, 0, 0, 0);
    }
    if (ch + 1 < NCH) {
      vm_wait0();  // next-chunk A landed (overlapped with MFMA above)
      c0 = n0; c1 = n1; c2 = n2; c3 = n3;
    }
  }
  if (hv == 1) *(f32x4*)&red[(tile * 64 + lane) * 4] = acc;
  __syncthreads();
  if (hv == 0) {
    f32x4 o4 = *(const f32x4*)&red[(tile * 64 + lane) * 4];
    float bb = bias[cbase + mr];
#pragma unroll
    for (int r = 0; r < 4; ++r) {
      float o = acc[r] + o4[r] + bb;
      int row = rbase + quad * 4 + r;  // C/D: col=lane&15, row=quad*4+reg
      if (do_gelu) {
        o = gelu_f(o);
        unsigned short h = bf16rn(o);
        unsigned short l = bf16rn(o - bf16hi_f(h));
        sth_sys(&Yhi[(size_t)row * NOUT + cbase + mr], (unsigned int)h);
        sth_sys(&Ylo[(size_t)row * NOUT + cbase + mr], (unsigned int)l);
      } else {
        st1_sys(&Yf32[(size_t)row * NOUT + cbase + mr], __float_as_uint(o));
      }
    }
  }
}

// ---- EPI: gates/blend/LN -> cs[slot_new]; recompute logits for pairs k-1, k
__device__ void epi_phase(const Par& p, int i, float* smem, float* sred) {
  int n = blockIdx.x;
  int t = threadIdx.x, wave = t >> 6, lane = t & 63;
  int Pn = 62 - i;
  int k = p.ksel[n];
  int slot_new = p.pos[n * 64 + k];
  float* s_wd1 = smem;          // [0, 8192)
  float* s_wd2 = smem + 8192;   // 64
  float* s_bd1 = smem + 8256;   // 64
  float* s_fnew = smem + 8320;  // 64
  float* sx = smem + 12544;     // x-row stash from sel
  if (i < 62) {
#pragma unroll
    for (int q = 0; q < 4; ++q)
      ((float4*)s_wd1)[q * 512 + t] = ((const float4*)p.Wd1)[q * 512 + t];
    if (t < 64) { s_wd2[t] = p.Wd2[t]; s_bd1[t] = p.bd1[t]; }
  }
  const float* ct = p.ct + (size_t)n * NOUT;
  int d = t;
  float lv = sx[d];
  float rv = sx[512 + d];
  unsigned int u0, u1, u2, u3;
  ld1_sys4(&ct[d], &ct[DMODEL + d], &ct[2 * DMODEL + d], &ct[3 * DMODEL + d],
           u0, u1, u2, u3);
  float c0 = __uint_as_float(u0), c1 = __uint_as_float(u1);
  float c2 = __uint_as_float(u2), c3 = __uint_as_float(u3);
  float s = sigm_f(c0) * lv + sigm_f(c1) * rv + sigm_f(c2) * c3;
  float part = wred_sum(s);
  if (lane == 0) sred[wave] = part;
  __syncthreads();
  float mm = 0.f;
#pragma unroll
  for (int ww = 0; ww < 8; ++ww) mm += sred[ww];
  mm *= (1.0f / 512.0f);
  float e = s - mm;
  float pq = wred_sum(e * e);
  if (lane == 0) sred[8 + wave] = pq;
  __syncthreads();
  float var = 0.f;
#pragma unroll
  for (int ww = 0; ww < 8; ++ww) var += sred[8 + ww];
  var *= (1.0f / 512.0f);
  float inv = 1.0f / sqrtf(var + 1e-5f);
  float nv = e * inv * p.gc[d] + p.btc[d];
  p.cs[(size_t)(n * 64 + slot_new) * DMODEL + d] = nv;  // block-local, cached
  if (i == 62) p.out[(size_t)n * DMODEL + d] = nv;
  if (d < FDIM) s_fnew[d] = nv;
  __syncthreads();
  if (i < 62) {
    if (wave == 0 && k >= 1) {
      const float* A = &p.cs[(size_t)(n * 64 + p.pos[n * 64 + (k - 1)]) * DMODEL];
      float hs = s_bd1[lane];
#pragma unroll 8
      for (int kk = 0; kk < 64; ++kk) hs += A[kk] * s_wd1[kk * 64 + lane];
#pragma unroll 8
      for (int kk = 0; kk < 64; ++kk) hs += s_fnew[kk] * s_wd1[(64 + kk) * 64 + lane];
      float g = wred_sum(gelu_f(hs) * s_wd2[lane]);
      if (lane == 0) p.logits[n * 64 + (k - 1)] = g + p.bd2[0];
    } else if (wave == 1 && k < Pn) {
      const float* Bv = &p.cs[(size_t)(n * 64 + p.pos[n * 64 + (k + 1)]) * DMODEL];
      float hs = s_bd1[lane];
#pragma unroll 8
      for (int kk = 0; kk < 64; ++kk) hs += s_fnew[kk] * s_wd1[kk * 64 + lane];
#pragma unroll 8
      for (int kk = 0; kk < 64; ++kk) hs += Bv[kk] * s_wd1[(64 + kk) * 64 + lane];
      float g = wred_sum(gelu_f(hs) * s_wd2[lane]);
      if (lane == 0) p.logits[n * 64 + k] = g + p.bd2[0];
    }
  }
}

__global__ void egt_zero(unsigned int* flags) { flags[threadIdx.x] = 0u; }

__global__ void __launch_bounds__(512, 2) egt_main(Par p) {
  __shared__ __align__(16) float smem[15872];  // 62 KB
  __shared__ float sred[16];
  __shared__ int sI[8];
  unsigned int nsync = 0;
  int b = blockIdx.x, t = threadIdx.x;
  int wave = t >> 6, lane = t & 63;

  // ---------- INIT-WTRANSFORM: Wc1/Wc2 fp32 -> B-frag-major bf16 hi/lo planes
  {
    int tid = b * 512 + t;
    for (int it = tid; it < 786432; it += 131072) {
      const float* W;
      unsigned short *dh, *dl;
      int nt, ks, l, KS2;
      if (it < 262144) {
        W = p.Wc1; dh = p.w1f; dl = p.w1f + W1PLANE;
        nt = it >> 11; int r2 = it & 2047; ks = r2 >> 6; l = r2 & 63; KS2 = 32;
      } else {
        int rem = it - 262144;
        W = p.Wc2; dh = p.w2f; dl = p.w2f + W2PLANE;
        nt = rem >> 12; int r2 = rem & 4095; ks = r2 >> 6; l = r2 & 63; KS2 = 64;
      }
      int k0 = ks * 32 + (l >> 4) * 8;
      int n = nt * 16 + (l & 15);
      unsigned int hw[4], lw[4];
#pragma unroll
      for (int jj = 0; jj < 4; ++jj) {
        float v0 = W[(size_t)(k0 + 2 * jj) * NOUT + n];
        float v1 = W[(size_t)(k0 + 2 * jj + 1) * NOUT + n];
        unsigned short h0 = bf16rn(v0), h1 = bf16rn(v1);
        unsigned short l0 = bf16rn(v0 - bf16hi_f(h0));
        unsigned short l1 = bf16rn(v1 - bf16hi_f(h1));
        hw[jj] = (unsigned int)h0 | ((unsigned int)h1 << 16);
        lw[jj] = (unsigned int)l0 | ((unsigned int)l1 << 16);
      }
      size_t o = ((size_t)nt * KS2 + ks) * 512 + l * 8;
      u32x4 H; H.x = hw[0]; H.y = hw[1]; H.z = hw[2]; H.w = hw[3];
      u32x4 L; L.x = lw[0]; L.y = lw[1]; L.z = lw[2]; L.w = lw[3];
      st4_sys(&dh[o], H);
      st4_sys(&dl[o], L);
    }
  }

  // ---------- INIT-PROJ: cs0 = LN(input @ Wi + bi); 32 (n,s)-rows per block
  {
    int rbase = b * 32;
    int n_ = b >> 1;
    float acc[32];
#pragma unroll
    for (int r = 0; r < 32; ++r) acc[r] = 0.f;
    float* xs = smem;  // [32][64]
    const float* Wi = p.Wi;
    for (int kc = 0; kc < 512; kc += 64) {
      __syncthreads();
      {
        int flat = t * 4;
        int r = flat >> 6, c = flat & 63;
        *(float4*)&xs[flat] =
            *(const float4*)&p.input[(size_t)(rbase + r) * 512 + kc + c];
      }
      __syncthreads();
      for (int k = 0; k < 64; k += 4) {
        float w0 = Wi[(size_t)(kc + k + 0) * 512 + t];
        float w1 = Wi[(size_t)(kc + k + 1) * 512 + t];
        float w2 = Wi[(size_t)(kc + k + 2) * 512 + t];
        float w3 = Wi[(size_t)(kc + k + 3) * 512 + t];
#pragma unroll
        for (int r = 0; r < 32; ++r) {
          float4 xv = *(const float4*)&xs[r * 64 + k];
          acc[r] += xv.x * w0 + xv.y * w1 + xv.z * w2 + xv.w * w3;
        }
      }
    }
    float* row8 = smem;  // [8][512]
#pragma unroll
    for (int chunk = 0; chunk < 4; ++chunk) {
      __syncthreads();
#pragma unroll
      for (int rr = 0; rr < 8; ++rr)
        row8[rr * 512 + t] = acc[chunk * 8 + rr] + p.bi[t];
      __syncthreads();
      int rr = wave;
      float vals[8];
      float sum = 0.f;
#pragma unroll
      for (int jj = 0; jj < 8; ++jj) {
        float v = row8[rr * 512 + jj * 64 + lane];
        vals[jj] = v;
        sum += v;
      }
      sum = wred_sum(sum);
      float mm = sum * (1.0f / 512.0f);
      float sq = 0.f;
#pragma unroll
      for (int jj = 0; jj < 8; ++jj) { float dd = vals[jj] - mm; sq += dd * dd; }
      sq = wred_sum(sq);
      float inv = 1.0f / sqrtf(sq * (1.0f / 512.0f) + 1e-5f);
      int r = chunk * 8 + rr;
      int ss = (b & 1) * 32 + r;
      float* dst = &p.cs[(size_t)(n_ * 64 + ss) * DMODEL];
#pragma unroll
      for (int jj = 0; jj < 8; ++jj) {
        int c = jj * 64 + lane;
        st1_sys(&dst[c], __float_as_uint((vals[jj] - mm) * inv * p.gi[c] + p.bti[c]));
      }
    }
  }
  gsync(p.flags, &nsync);

  // ---------- INIT-SCORE: 63 pair logits per row; init pos; SEL(0)
  if (b < NBATCH) {
    int n = b;
    float* s_wd1 = smem;          // 8192 floats
    float* s_f = smem + 8192;     // 4096 floats
    float* s_wd2 = smem + 12288;  // 64
    float* s_bd1 = smem + 12352;  // 64
#pragma unroll
    for (int q = 0; q < 4; ++q)
      ((float4*)s_wd1)[q * 512 + t] = ((const float4*)p.Wd1)[q * 512 + t];
#pragma unroll
    for (int q = 0; q < 2; ++q) {
      int i4 = q * 512 + t;
      int s = i4 >> 4, c = (i4 & 15) * 4;
      *(float4*)&s_f[s * 64 + c] =
          *(const float4*)&p.cs[(size_t)(n * 64 + s) * DMODEL + c];
    }
    if (t < 64) {
      s_wd2[t] = p.Wd2[t];
      s_bd1[t] = p.bd1[t];
      p.pos[n * 64 + t] = t;
    }
    __syncthreads();
    for (int pr = wave; pr < 63; pr += 8) {
      float hs = s_bd1[lane];
#pragma unroll 8
      for (int kk = 0; kk < 64; ++kk) hs += s_f[pr * 64 + kk] * s_wd1[kk * 64 + lane];
#pragma unroll 8
      for (int kk = 0; kk < 64; ++kk) hs += s_f[(pr + 1) * 64 + kk] * s_wd1[(64 + kk) * 64 + lane];
      float g = wred_sum(gelu_f(hs) * s_wd2[lane]);
      if (lane == 0) p.logits[n * 64 + pr] = g + p.bd2[0];
    }
    __syncthreads();
    sel_phase(p, 0, sI, smem);
  }
  gsync(p.flags, &nsync);

  // ---------- main serial loop
  for (int i = 0; i < 63; ++i) {
    gemm_mfma(p.xhi, p.xlo, p.w1f, W1PLANE, p.bc1, KIN, 32, 2, true,
              p.hhi, p.hlo, nullptr, smem);
    gsync(p.flags, &nsync);
    gemm_mfma(p.hhi, p.hlo, p.w2f, W2PLANE, p.bc2, NOUT, 64, 4, false,
              nullptr, nullptr, p.ct, smem);
    gsync(p.flags, &nsync);
    if (b < NBATCH) {
      epi_phase(p, i, smem, sred);
      if (i < 62) {
        __syncthreads();
        sel_phase(p, i + 1, sI, smem);
      }
    }
    gsync(p.flags, &nsync);
  }
}

extern "C" void kernel_launch(void* const* d_in, const int* in_sizes, int n_in,
                              void* d_out, int out_size, void* d_ws, size_t ws_size,
                              hipStream_t stream) {
  Par p;
  p.input = (const float*)d_in[0];
  p.mask = (const float*)d_in[1];
  p.Wi = (const float*)d_in[2];
  p.bi = (const float*)d_in[3];
  p.gi = (const float*)d_in[4];
  p.bti = (const float*)d_in[5];
  p.Wd1 = (const float*)d_in[6];
  p.bd1 = (const float*)d_in[7];
  p.Wd2 = (const float*)d_in[8];
  p.bd2 = (const float*)d_in[9];
  p.Wc1 = (const float*)d_in[10];
  p.bc1 = (const float*)d_in[11];
  p.Wc2 = (const float*)d_in[12];
  p.bc2 = (const float*)d_in[13];
  p.gc = (const float*)d_in[14];
  p.btc = (const float*)d_in[15];
  p.out = (float*)d_out;

  char* ws = (char*)d_ws;
  size_t off = 0;
  auto take = [&](size_t bytes) -> char* {
    char* r = ws + off;
    off += (bytes + 255) & ~(size_t)255;
    return r;
  };
  p.flags = (unsigned int*)take(1024);
  p.pos = (int*)take(128 * 64 * 4);
  p.ksel = (int*)take(128 * 4);
  p.logits = (float*)take(128 * 64 * 4);
  p.ct = (float*)take((size_t)128 * 2048 * 4);
  p.cs = (float*)take((size_t)128 * 64 * 512 * 4);
  p.xhi = (unsigned short*)take((size_t)128 * 1024 * 2);
  p.xlo = (unsigned short*)take((size_t)128 * 1024 * 2);
  p.hhi = (unsigned short*)take((size_t)128 * 2048 * 2);
  p.hlo = (unsigned short*)take((size_t)128 * 2048 * 2);
  p.w1f = (unsigned short*)take((size_t)2 * W1PLANE * 2);
  p.w2f = (unsigned short*)take((size_t)2 * W2PLANE * 2);
  // total ~43.5 MB of d_ws

  hipLaunchKernelGGL(egt_zero, dim3(1), dim3(256), 0, stream, p.flags);
  void* args[] = {&p};
  hipError_t err = hipLaunchCooperativeKernel(egt_main, dim3(256), dim3(512), args, 0, stream);
  if (err != hipSuccess) {
    (void)hipGetLastError();  // manual barrier works under plain launch too
    hipLaunchKernelGGL(egt_main, dim3(256), dim3(512), 0, stream, p);
  }
}

// Round 12
// 2440.090 us; speedup vs baseline: 1.8029x; 1.1020x over previous
//
#include <hip/hip_runtime.h>

#define NBATCH 128
#define DMODEL 512
#define FDIM 64
#define KIN 1024
#define NOUT 2048

typedef __attribute__((ext_vector_type(8))) short bf16x8;
typedef __attribute__((ext_vector_type(4))) float f32x4;
typedef __attribute__((ext_vector_type(4))) unsigned int u32x4;
typedef __attribute__((ext_vector_type(2))) unsigned int u32x2;

struct Par {
  const float *input, *mask, *Wi, *bi, *gi, *bti;
  const float *Wd1, *bd1, *Wd2, *bd2;
  const float *Wc1, *bc1, *Wc2, *bc2, *gc, *btc;
  float *out;
  float *cs, *ct, *logits;
  unsigned short *xhi, *xlo, *hhi, *hlo, *w1f, *w2f;
  int *pos, *ksel;
  unsigned int *flags;
};

#define W1PLANE 2097152u   // 128*32*512 u16 per plane
#define W2PLANE 4194304u   // 128*64*512 u16 per plane

__device__ __forceinline__ float gelu_f(float v) {
  float u = 0.7978845608028654f * (v + 0.044715f * v * v * v);
  return 0.5f * v * (1.0f + tanhf(u));
}
__device__ __forceinline__ float sigm_f(float v) { return 1.0f / (1.0f + expf(-v)); }

__device__ __forceinline__ float wred_sum(float v) {
#pragma unroll
  for (int o = 32; o > 0; o >>= 1) v += __shfl_xor(v, o, 64);
  return v;
}

__device__ __forceinline__ unsigned short bf16rn(float v) {
  unsigned int u = __float_as_uint(v);
  return (unsigned short)((u + 0x7FFFu + ((u >> 16) & 1u)) >> 16);
}
__device__ __forceinline__ float bf16hi_f(unsigned short h) {
  return __uint_as_float(((unsigned int)h) << 16);
}

// ---- system-coherent (L1/L2-bypass, LLC-allocating) stream accessors.
__device__ __forceinline__ void ldx4_issue(const void* p0, const void* p1,
                                           const void* p2, const void* p3,
                                           u32x4& a, u32x4& b, u32x4& c, u32x4& d) {
  asm volatile(
      "global_load_dwordx4 %0, %4, off sc0 sc1\n\t"
      "global_load_dwordx4 %1, %5, off sc0 sc1\n\t"
      "global_load_dwordx4 %2, %6, off sc0 sc1\n\t"
      "global_load_dwordx4 %3, %7, off sc0 sc1"
      : "=&v"(a), "=&v"(b), "=&v"(c), "=&v"(d)
      : "v"(p0), "v"(p1), "v"(p2), "v"(p3)
      : "memory");
}
__device__ __forceinline__ void vm_wait0() {
  asm volatile("s_waitcnt vmcnt(0)" ::: "memory");
}
__device__ __forceinline__ void ld1_sys4(const void* p0, const void* p1,
                                         const void* p2, const void* p3,
                                         unsigned int& a, unsigned int& b,
                                         unsigned int& c, unsigned int& d) {
  asm volatile(
      "global_load_dword %0, %4, off sc0 sc1\n\t"
      "global_load_dword %1, %5, off sc0 sc1\n\t"
      "global_load_dword %2, %6, off sc0 sc1\n\t"
      "global_load_dword %3, %7, off sc0 sc1\n\t"
      "s_waitcnt vmcnt(0)"
      : "=&v"(a), "=&v"(b), "=&v"(c), "=&v"(d)
      : "v"(p0), "v"(p1), "v"(p2), "v"(p3)
      : "memory");
}
__device__ __forceinline__ unsigned int ld1_sys(const void* p) {
  unsigned int r;
  asm volatile("global_load_dword %0, %1, off sc0 sc1\n\ts_waitcnt vmcnt(0)"
               : "=&v"(r) : "v"(p) : "memory");
  return r;
}
__device__ __forceinline__ void st1_sys(void* p, unsigned int v) {
  asm volatile("global_store_dword %0, %1, off sc0 sc1" :: "v"(p), "v"(v) : "memory");
}
__device__ __forceinline__ void st2_sys(void* p, u32x2 v) {
  asm volatile("global_store_dwordx2 %0, %1, off sc0 sc1" :: "v"(p), "v"(v) : "memory");
}
__device__ __forceinline__ void st4_sys(void* p, u32x4 v) {
  asm volatile("global_store_dwordx4 %0, %1, off sc0 sc1" :: "v"(p), "v"(v) : "memory");
}
__device__ __forceinline__ void sth_sys(void* p, unsigned int v) {
  asm volatile("global_store_short %0, %1, off sc0 sc1" :: "v"(p), "v"(v) : "memory");
}

// ---- hierarchical grid barrier: 8 per-group counters (separate cache lines),
// RELAXED agent-scope atomic arrival (no cache maintenance emitted), 8 pollers.
// Data visibility comes from the explicit vmcnt(0) drain of sc0sc1 stores.
__device__ __forceinline__ void gsync(unsigned int* flags, unsigned int* gen) {
  unsigned int g = ++(*gen);
  asm volatile("s_waitcnt vmcnt(0) lgkmcnt(0)" ::: "memory");
  __syncthreads();  // all threads' bypass stores drained
  int t = threadIdx.x;
  if (t == 0) {
    __hip_atomic_fetch_add(&flags[(blockIdx.x & 7) * 32], 1u,
                           __ATOMIC_RELAXED, __HIP_MEMORY_SCOPE_AGENT);
  }
  if (t < 8) {
    unsigned int tgt = g * 32u;  // 32 blocks per counter
    while (ld1_sys(&flags[t * 32]) < tgt) __builtin_amdgcn_s_sleep(1);
  }
  __syncthreads();
}

// ---- SEL: argmax + pos/logit shift; emit x = [l,r] as bf16 hi/lo planes + LDS fp32 stash
__device__ void sel_phase(const Par& p, int i, int* sI, float* smem) {
  int n = blockIdx.x;
  int t = threadIdx.x, wave = t >> 6, lane = t & 63;
  int P = 63 - i;
  if (wave == 0) {
    float v = -3.0e38f;
    int idx = 1 << 20;
    if (lane < P) {
      v = p.logits[n * 64 + lane];
      float mk = p.mask[n * 64 + i + 1 + lane];
      if (!(mk > 0.0f)) v = -1.0e9f;
      idx = lane;
    }
#pragma unroll
    for (int o = 32; o > 0; o >>= 1) {
      float v2 = __shfl_xor(v, o, 64);
      int i2 = __shfl_xor(idx, o, 64);
      if (v2 > v || (v2 == v && i2 < idx)) { v = v2; idx = i2; }
    }
    if (lane == 0) {
      p.ksel[n] = idx;
      sI[0] = idx;
      sI[1] = p.pos[n * 64 + idx];
      sI[2] = p.pos[n * 64 + idx + 1];
    }
  }
  __syncthreads();
  int k = sI[0], slot_l = sI[1], slot_r = sI[2];
  if (wave == 1) {  // shift pos (wave-lockstep load-before-store)
    int j = lane;
    if (j >= k + 1 && j <= 62 - i) {
      int tmp = p.pos[n * 64 + j + 1];
      p.pos[n * 64 + j] = tmp;
    }
  } else if (wave == 2) {  // shift logits
    int j = lane;
    if (j >= k && j <= 61 - i) {
      float tmp = p.logits[n * 64 + j + 1];
      p.logits[n * 64 + j] = tmp;
    }
  }
  float* sx = smem + 12544;  // survives g1/g2 (they use floats [0,12544))
  if (t < 256) {
    const float* srcp = (t < 128) ? &p.cs[(size_t)(n * 64 + slot_l) * DMODEL]
                                  : &p.cs[(size_t)(n * 64 + slot_r) * DMODEL];
    int so = (t & 127) * 4;
    int o = (t < 128) ? so : (512 + so);
    float4 v = *(const float4*)&srcp[so];
    *(float4*)&sx[o] = v;
    ushort4 hi, lo;
    hi.x = bf16rn(v.x); lo.x = bf16rn(v.x - bf16hi_f(hi.x));
    hi.y = bf16rn(v.y); lo.y = bf16rn(v.y - bf16hi_f(hi.y));
    hi.z = bf16rn(v.z); lo.z = bf16rn(v.z - bf16hi_f(hi.z));
    hi.w = bf16rn(v.w); lo.w = bf16rn(v.w - bf16hi_f(hi.w));
    u32x2 uh, ul;
    uh.x = (unsigned)hi.x | ((unsigned)hi.y << 16);
    uh.y = (unsigned)hi.z | ((unsigned)hi.w << 16);
    ul.x = (unsigned)lo.x | ((unsigned)lo.y << 16);
    ul.y = (unsigned)lo.z | ((unsigned)lo.w << 16);
    st2_sys(&p.xhi[(size_t)n * KIN + o], uh);
    st2_sys(&p.xlo[(size_t)n * KIN + o], ul);
  }
}

// ---- split-bf16 MFMA GEMM with cross-chunk A-prefetch; B inline from L2.
__device__ void gemm_mfma(const unsigned short* Ahi, const unsigned short* Alo,
                          const unsigned short* Bf, unsigned int bplane,
                          const float* bias, int K, int KS, int NCH, bool do_gelu,
                          unsigned short* Yhi, unsigned short* Ylo, float* Yf32,
                          float* smem) {
  int b = blockIdx.x, t = threadIdx.x;
  int m = (b >> 3) & 7;
  int ng = ((b >> 6) << 3) | (b & 7);
  int rbase = m * 16;
  int w = t >> 6, lane = t & 63;
  int tile = w & 3, hv = w >> 2;
  int quad = lane >> 4, mr = lane & 15;
  int nt = ng * 4 + tile;
  int cbase = nt * 16;
  unsigned short* As = (unsigned short*)smem;  // [pl][hv][16][264] u16
  float* red = smem + 8448;                    // 4096 floats
  int KH = K >> 1;
  f32x4 acc = {0.f, 0.f, 0.f, 0.f};
  const unsigned short* bp0 = Bf + (size_t)nt * KS * 512 + lane * 8;
  const unsigned short* bp1 = bp0 + bplane;
  const unsigned short* srcb[4];
  size_t aoff[4];
  int lo_[4];
#pragma unroll
  for (int q = 0; q < 4; ++q) {
    int g = q * 512 + t;
    int pl = g >> 10, hh = (g >> 9) & 1, r = (g >> 5) & 15, kg = g & 31;
    srcb[q] = pl ? Alo : Ahi;
    aoff[q] = (size_t)(rbase + r) * K + hh * KH + kg * 8;
    lo_[q] = ((pl * 2 + hh) * 16 + r) * 264 + kg * 8;
  }
  u32x4 c0, c1, c2, c3, n0, n1, n2, n3;
  ldx4_issue(srcb[0] + aoff[0], srcb[1] + aoff[1], srcb[2] + aoff[2],
             srcb[3] + aoff[3], c0, c1, c2, c3);
  vm_wait0();
  for (int ch = 0; ch < NCH; ++ch) {
    __syncthreads();  // previous chunk's readers done
    *(u32x4*)&As[lo_[0]] = c0;
    *(u32x4*)&As[lo_[1]] = c1;
    *(u32x4*)&As[lo_[2]] = c2;
    *(u32x4*)&As[lo_[3]] = c3;
    __syncthreads();  // tile visible
    if (ch + 1 < NCH) {  // prefetch next chunk's A (in flight during MFMA)
      size_t o = (size_t)(ch + 1) * 256;
      ldx4_issue(srcb[0] + aoff[0] + o, srcb[1] + aoff[1] + o,
                 srcb[2] + aoff[2] + o, srcb[3] + aoff[3] + o, n0, n1, n2, n3);
    }
    int ks0 = hv * (KS >> 1) + ch * 8;
    const unsigned short* a0 = &As[(hv * 16 + mr) * 264 + quad * 8];
    const unsigned short* a1 = &As[((2 + hv) * 16 + mr) * 264 + quad * 8];
#pragma unroll
    for (int s = 0; s < 8; ++s) {
      bf16x8 ah = *(const bf16x8*)(a0 + s * 32);
      bf16x8 al = *(const bf16x8*)(a1 + s * 32);
      bf16x8 bh = *(const bf16x8*)(bp0 + (size_t)(ks0 + s) * 512);
      bf16x8 bl = *(const bf16x8*)(bp1 + (size_t)(ks0 + s) * 512);
      acc = __builtin_amdgcn_mfma_f32_16x16x32_bf16(ah, bh, acc, 0, 0, 0);
      acc = __builtin_amdgcn_mfma_f32_16x16x32_bf16(ah, bl, acc, 0, 0, 0);
      acc = __builtin_amdgcn_mfma_f32_16x16x32_bf16(al, bh, acc, 0, 0, 0);
    }
    if (ch + 1 < NCH) {
      vm_wait0();  // next-chunk A landed (overlapped with MFMA above)
      c0 = n0; c1 = n1; c2 = n2; c3 = n3;
    }
  }
  if (hv == 1) *(f32x4*)&red[(tile * 64 + lane) * 4] = acc;
  __syncthreads();
  if (hv == 0) {
    f32x4 o4 = *(const f32x4*)&red[(tile * 64 + lane) * 4];
    float bb = bias[cbase + mr];
#pragma unroll
    for (int r = 0; r < 4; ++r) {
      float o = acc[r] + o4[r] + bb;
      int row = rbase + quad * 4 + r;  // C/D: col=lane&15, row=quad*4+reg
      if (do_gelu) {
        o = gelu_f(o);
        unsigned short h = bf16rn(o);
        unsigned short l = bf16rn(o - bf16hi_f(h));
        sth_sys(&Yhi[(size_t)row * NOUT + cbase + mr], (unsigned int)h);
        sth_sys(&Ylo[(size_t)row * NOUT + cbase + mr], (unsigned int)l);
      } else {
        st1_sys(&Yf32[(size_t)row * NOUT + cbase + mr], __float_as_uint(o));
      }
    }
  }
}

// ---- EPI: gates/blend/LN -> cs[slot_new]; recompute logits for pairs k-1, k
__device__ void epi_phase(const Par& p, int i, float* smem, float* sred) {
  int n = blockIdx.x;
  int t = threadIdx.x, wave = t >> 6, lane = t & 63;
  int Pn = 62 - i;
  int k = p.ksel[n];
  int slot_new = p.pos[n * 64 + k];
  float* s_wd1 = smem;          // [0, 8192)
  float* s_wd2 = smem + 8192;   // 64
  float* s_bd1 = smem + 8256;   // 64
  float* s_fnew = smem + 8320;  // 64
  float* sx = smem + 12544;     // x-row stash from sel
  if (i < 62) {
#pragma unroll
    for (int q = 0; q < 4; ++q)
      ((float4*)s_wd1)[q * 512 + t] = ((const float4*)p.Wd1)[q * 512 + t];
    if (t < 64) { s_wd2[t] = p.Wd2[t]; s_bd1[t] = p.bd1[t]; }
  }
  const float* ct = p.ct + (size_t)n * NOUT;
  int d = t;
  float lv = sx[d];
  float rv = sx[512 + d];
  unsigned int u0, u1, u2, u3;
  ld1_sys4(&ct[d], &ct[DMODEL + d], &ct[2 * DMODEL + d], &ct[3 * DMODEL + d],
           u0, u1, u2, u3);
  float c0 = __uint_as_float(u0), c1 = __uint_as_float(u1);
  float c2 = __uint_as_float(u2), c3 = __uint_as_float(u3);
  float s = sigm_f(c0) * lv + sigm_f(c1) * rv + sigm_f(c2) * c3;
  float part = wred_sum(s);
  if (lane == 0) sred[wave] = part;
  __syncthreads();
  float mm = 0.f;
#pragma unroll
  for (int ww = 0; ww < 8; ++ww) mm += sred[ww];
  mm *= (1.0f / 512.0f);
  float e = s - mm;
  float pq = wred_sum(e * e);
  if (lane == 0) sred[8 + wave] = pq;
  __syncthreads();
  float var = 0.f;
#pragma unroll
  for (int ww = 0; ww < 8; ++ww) var += sred[8 + ww];
  var *= (1.0f / 512.0f);
  float inv = 1.0f / sqrtf(var + 1e-5f);
  float nv = e * inv * p.gc[d] + p.btc[d];
  p.cs[(size_t)(n * 64 + slot_new) * DMODEL + d] = nv;  // block-local, cached
  if (i == 62) p.out[(size_t)n * DMODEL + d] = nv;
  if (d < FDIM) s_fnew[d] = nv;
  __syncthreads();
  if (i < 62) {
    if (wave == 0 && k >= 1) {
      const float* A = &p.cs[(size_t)(n * 64 + p.pos[n * 64 + (k - 1)]) * DMODEL];
      float hs = s_bd1[lane];
#pragma unroll 8
      for (int kk = 0; kk < 64; ++kk) hs += A[kk] * s_wd1[kk * 64 + lane];
#pragma unroll 8
      for (int kk = 0; kk < 64; ++kk) hs += s_fnew[kk] * s_wd1[(64 + kk) * 64 + lane];
      float g = wred_sum(gelu_f(hs) * s_wd2[lane]);
      if (lane == 0) p.logits[n * 64 + (k - 1)] = g + p.bd2[0];
    } else if (wave == 1 && k < Pn) {
      const float* Bv = &p.cs[(size_t)(n * 64 + p.pos[n * 64 + (k + 1)]) * DMODEL];
      float hs = s_bd1[lane];
#pragma unroll 8
      for (int kk = 0; kk < 64; ++kk) hs += s_fnew[kk] * s_wd1[kk * 64 + lane];
#pragma unroll 8
      for (int kk = 0; kk < 64; ++kk) hs += Bv[kk] * s_wd1[(64 + kk) * 64 + lane];
      float g = wred_sum(gelu_f(hs) * s_wd2[lane]);
      if (lane == 0) p.logits[n * 64 + k] = g + p.bd2[0];
    }
  }
}

__global__ void egt_zero(unsigned int* flags) { flags[threadIdx.x] = 0u; }

__global__ void __launch_bounds__(512, 2) egt_main(Par p) {
  __shared__ __align__(16) float smem[15872];  // 62 KB
  __shared__ float sred[16];
  __shared__ int sI[8];
  unsigned int nsync = 0;
  int b = blockIdx.x, t = threadIdx.x;
  int wave = t >> 6, lane = t & 63;

  // ---------- INIT-WTRANSFORM: Wc1/Wc2 fp32 -> B-frag-major bf16 hi/lo planes
  {
    int tid = b * 512 + t;
    for (int it = tid; it < 786432; it += 131072) {
      const float* W;
      unsigned short *dh, *dl;
      int nt, ks, l, KS2;
      if (it < 262144) {
        W = p.Wc1; dh = p.w1f; dl = p.w1f + W1PLANE;
        nt = it >> 11; int r2 = it & 2047; ks = r2 >> 6; l = r2 & 63; KS2 = 32;
      } else {
        int rem = it - 262144;
        W = p.Wc2; dh = p.w2f; dl = p.w2f + W2PLANE;
        nt = rem >> 12; int r2 = rem & 4095; ks = r2 >> 6; l = r2 & 63; KS2 = 64;
      }
      int k0 = ks * 32 + (l >> 4) * 8;
      int n = nt * 16 + (l & 15);
      unsigned int hw[4], lw[4];
#pragma unroll
      for (int jj = 0; jj < 4; ++jj) {
        float v0 = W[(size_t)(k0 + 2 * jj) * NOUT + n];
        float v1 = W[(size_t)(k0 + 2 * jj + 1) * NOUT + n];
        unsigned short h0 = bf16rn(v0), h1 = bf16rn(v1);
        unsigned short l0 = bf16rn(v0 - bf16hi_f(h0));
        unsigned short l1 = bf16rn(v1 - bf16hi_f(h1));
        hw[jj] = (unsigned int)h0 | ((unsigned int)h1 << 16);
        lw[jj] = (unsigned int)l0 | ((unsigned int)l1 << 16);
      }
      size_t o = ((size_t)nt * KS2 + ks) * 512 + l * 8;
      u32x4 H; H.x = hw[0]; H.y = hw[1]; H.z = hw[2]; H.w = hw[3];
      u32x4 L; L.x = lw[0]; L.y = lw[1]; L.z = lw[2]; L.w = lw[3];
      st4_sys(&dh[o], H);
      st4_sys(&dl[o], L);
    }
  }

  // ---------- INIT-PROJ: cs0 = LN(input @ Wi + bi); 32 (n,s)-rows per block
  {
    int rbase = b * 32;
    int n_ = b >> 1;
    float acc[32];
#pragma unroll
    for (int r = 0; r < 32; ++r) acc[r] = 0.f;
    float* xs = smem;  // [32][64]
    const float* Wi = p.Wi;
    for (int kc = 0; kc < 512; kc += 64) {
      __syncthreads();
      {
        int flat = t * 4;
        int r = flat >> 6, c = flat & 63;
        *(float4*)&xs[flat] =
            *(const float4*)&p.input[(size_t)(rbase + r) * 512 + kc + c];
      }
      __syncthreads();
      for (int k = 0; k < 64; k += 4) {
        float w0 = Wi[(size_t)(kc + k + 0) * 512 + t];
        float w1 = Wi[(size_t)(kc + k + 1) * 512 + t];
        float w2 = Wi[(size_t)(kc + k + 2) * 512 + t];
        float w3 = Wi[(size_t)(kc + k + 3) * 512 + t];
#pragma unroll
        for (int r = 0; r < 32; ++r) {
          float4 xv = *(const float4*)&xs[r * 64 + k];
          acc[r] += xv.x * w0 + xv.y * w1 + xv.z * w2 + xv.w * w3;
        }
      }
    }
    float* row8 = smem;  // [8][512]
#pragma unroll
    for (int chunk = 0; chunk < 4; ++chunk) {
      __syncthreads();
#pragma unroll
      for (int rr = 0; rr < 8; ++rr)
        row8[rr * 512 + t] = acc[chunk * 8 + rr] + p.bi[t];
      __syncthreads();
      int rr = wave;
      float vals[8];
      float sum = 0.f;
#pragma unroll
      for (int jj = 0; jj < 8; ++jj) {
        float v = row8[rr * 512 + jj * 64 + lane];
        vals[jj] = v;
        sum += v;
      }
      sum = wred_sum(sum);
      float mm = sum * (1.0f / 512.0f);
      float sq = 0.f;
#pragma unroll
      for (int jj = 0; jj < 8; ++jj) { float dd = vals[jj] - mm; sq += dd * dd; }
      sq = wred_sum(sq);
      float inv = 1.0f / sqrtf(sq * (1.0f / 512.0f) + 1e-5f);
      int r = chunk * 8 + rr;
      int ss = (b & 1) * 32 + r;
      float* dst = &p.cs[(size_t)(n_ * 64 + ss) * DMODEL];
#pragma unroll
      for (int jj = 0; jj < 8; ++jj) {
        int c = jj * 64 + lane;
        st1_sys(&dst[c], __float_as_uint((vals[jj] - mm) * inv * p.gi[c] + p.bti[c]));
      }
    }
  }
  gsync(p.flags, &nsync);

  // ---------- INIT-SCORE: 63 pair logits per row; init pos; SEL(0)
  if (b < NBATCH) {
    int n = b;
    float* s_wd1 = smem;          // 8192 floats
    float* s_f = smem + 8192;     // 4096 floats
    float* s_wd2 = smem + 12288;  // 64
    float* s_bd1 = smem + 12352;  // 64
#pragma unroll
    for (int q = 0; q < 4; ++q)
      ((float4*)s_wd1)[q * 512 + t] = ((const float4*)p.Wd1)[q * 512 + t];
#pragma unroll
    for (int q = 0; q < 2; ++q) {
      int i4 = q * 512 + t;
      int s = i4 >> 4, c = (i4 & 15) * 4;
      *(float4*)&s_f[s * 64 + c] =
          *(const float4*)&p.cs[(size_t)(n * 64 + s) * DMODEL + c];
    }
    if (t < 64) {
      s_wd2[t] = p.Wd2[t];
      s_bd1[t] = p.bd1[t];
      p.pos[n * 64 + t] = t;
    }
    __syncthreads();
    for (int pr = wave; pr < 63; pr += 8) {
      float hs = s_bd1[lane];
#pragma unroll 8
      for (int kk = 0; kk < 64; ++kk) hs += s_f[pr * 64 + kk] * s_wd1[kk * 64 + lane];
#pragma unroll 8
      for (int kk = 0; kk < 64; ++kk) hs += s_f[(pr + 1) * 64 + kk] * s_wd1[(64 + kk) * 64 + lane];
      float g = wred_sum(gelu_f(hs) * s_wd2[lane]);
      if (lane == 0) p.logits[n * 64 + pr] = g + p.bd2[0];
    }
    __syncthreads();
    sel_phase(p, 0, sI, smem);
  }
  gsync(p.flags, &nsync);

  // ---------- main serial loop
  for (int i = 0; i < 63; ++i) {
    gemm_mfma(p.xhi, p.xlo, p.w1f, W1PLANE, p.bc1, KIN, 32, 2, true,
              p.hhi, p.hlo, nullptr, smem);
    gsync(p.flags, &nsync);
    gemm_mfma(p.hhi, p.hlo, p.w2f, W2PLANE, p.bc2, NOUT, 64, 4, false,
              nullptr, nullptr, p.ct, smem);
    gsync(p.flags, &nsync);
    if (b < NBATCH) {
      epi_phase(p, i, smem, sred);
      if (i < 62) {
        __syncthreads();
        sel_phase(p, i + 1, sI, smem);
      }
    }
    gsync(p.flags, &nsync);
  }
}

extern "C" void kernel_launch(void* const* d_in, const int* in_sizes, int n_in,
                              void* d_out, int out_size, void* d_ws, size_t ws_size,
                              hipStream_t stream) {
  Par p;
  p.input = (const float*)d_in[0];
  p.mask = (const float*)d_in[1];
  p.Wi = (const float*)d_in[2];
  p.bi = (const float*)d_in[3];
  p.gi = (const float*)d_in[4];
  p.bti = (const float*)d_in[5];
  p.Wd1 = (const float*)d_in[6];
  p.bd1 = (const float*)d_in[7];
  p.Wd2 = (const float*)d_in[8];
  p.bd2 = (const float*)d_in[9];
  p.Wc1 = (const float*)d_in[10];
  p.bc1 = (const float*)d_in[11];
  p.Wc2 = (const float*)d_in[12];
  p.bc2 = (const float*)d_in[13];
  p.gc = (const float*)d_in[14];
  p.btc = (const float*)d_in[15];
  p.out = (float*)d_out;

  char* ws = (char*)d_ws;
  size_t off = 0;
  auto take = [&](size_t bytes) -> char* {
    char* r = ws + off;
    off += (bytes + 255) & ~(size_t)255;
    return r;
  };
  p.flags = (unsigned int*)take(1024);
  p.pos = (int*)take(128 * 64 * 4);
  p.ksel = (int*)take(128 * 4);
  p.logits = (float*)take(128 * 64 * 4);
  p.ct = (float*)take((size_t)128 * 2048 * 4);
  p.cs = (float*)take((size_t)128 * 64 * 512 * 4);
  p.xhi = (unsigned short*)take((size_t)128 * 1024 * 2);
  p.xlo = (unsigned short*)take((size_t)128 * 1024 * 2);
  p.hhi = (unsigned short*)take((size_t)128 * 2048 * 2);
  p.hlo = (unsigned short*)take((size_t)128 * 2048 * 2);
  p.w1f = (unsigned short*)take((size_t)2 * W1PLANE * 2);
  p.w2f = (unsigned short*)take((size_t)2 * W2PLANE * 2);
  // total ~43.5 MB of d_ws

  hipLaunchKernelGGL(egt_zero, dim3(1), dim3(256), 0, stream, p.flags);
  void* args[] = {&p};
  hipError_t err = hipLaunchCooperativeKernel(egt_main, dim3(256), dim3(512), args, 0, stream);
  if (err != hipSuccess) {
    (void)hipGetLastError();  // manual barrier works under plain launch too
    hipLaunchKernelGGL(egt_main, dim3(256), dim3(512), 0, stream, p);
  }
}